// Round 2
// baseline (236.245 us; speedup 1.0000x reference)
//
#include <hip/hip_runtime.h>

// SplineFilter: out[b,n,f] = eval_x[b,n,f] * sf^2,
//   sf = sum_k basis_k(eigs[b,n]) * coeffs[k,f]
// Cubic B-spline over uniform knots linspace(0,2,16), 12 bases; only 4
// nonzero taps per x (cardinal cubic weights in t = x*7.5 - i).
//
// Memory-bound: 269.5 MB irreducible traffic -> ~43 us @ 6.3 TB/s.
// R1 post-mortem: branch-free + padded-LDS-table + load reordering was
// NEUTRAL -> kernel is BW-bound, not issue-bound. This round's single
// A/B variable: remove non-temporal load/store. Rationale: the 6.3 TB/s
// measured copy ceiling (m13) and the harness's own 6.6 TB/s fills both
// use the normal L2-allocating path; NT forces the full 134 MB write
// stream straight to HBM, while the normal path lets the 256 MB L3
// absorb part of it. Everything else is identical to R1.

#define N_BASES 12
#define F_CH 128
#define CHUNKS 4
#define PAD 3
#define TAB_ROWS (N_BASES + 2 * PAD)  // 18 rows: k = -3..14
#define ROW_VF4 (F_CH / 4)            // 32 vf4 per row

typedef float vf4 __attribute__((ext_vector_type(4)));

template <bool EXACT>
__global__ __launch_bounds__(256) void spline_filter_kernel(
    const vf4* __restrict__ x4,      // eval_x as vf4
    const float* __restrict__ eigs,  // [rows]
    const vf4* __restrict__ coeffs4, // [12*32]
    vf4*       __restrict__ out4,
    int total4, int stride4)
{
    __shared__ vf4 sc[TAB_ROWS * ROW_VF4];  // 9 KB, zero-padded

    const int t = threadIdx.x;
    for (int r = t; r < TAB_ROWS * ROW_VF4; r += 256) {
        const int k = (r >> 5) - PAD;
        sc[r] = ((unsigned)k < (unsigned)N_BASES)
                    ? coeffs4[k * ROW_VF4 + (r & 31)]
                    : (vf4)0.0f;
    }
    __syncthreads();

    const int gid = blockIdx.x * 256 + t;

    float eg[CHUNKS];
    vf4   xv[CHUNKS];

    // Issue the loads the long dependency chain needs FIRST.
    #pragma unroll
    for (int c = 0; c < CHUNKS; ++c) {
        const int idx = gid + c * stride4;
        if (EXACT || idx < total4) eg[c] = eigs[idx >> 5];
        else                       eg[c] = 0.0f;
    }
    #pragma unroll
    for (int c = 0; c < CHUNKS; ++c) {
        const int idx = gid + c * stride4;
        if (EXACT || idx < total4) xv[c] = x4[idx];   // plain load (A/B: no NT)
        else                       xv[c] = (vf4)0.0f;
    }

    // stride4 is a multiple of 32, so lane is chunk-invariant.
    const int lane = gid & 31;

    #pragma unroll
    for (int c = 0; c < CHUNKS; ++c) {
        const int idx = gid + c * stride4;
        if (!EXACT && idx >= total4) continue;

        // 4 nonzero cardinal cubic weights for x = eg[c]
        const float u = eg[c] * 7.5f;          // x / (2/15)
        int i = (int)u;
        i = min(max(i, 0), N_BASES + 2);       // rows i..i+3 stay in-table
        float tt = u - (float)i;
        tt = fminf(fmaxf(tt, 0.0f), 1.0f);     // OOB x -> all taps hit zero rows
        const float t2  = tt * tt;
        const float t3  = t2 * tt;
        const float omt = 1.0f - tt;
        const float w0 = omt * omt * omt * (1.0f / 6.0f);                        // k=i-3
        const float w1 = (3.0f * t3 - 6.0f * t2 + 4.0f) * (1.0f / 6.0f);         // k=i-2
        const float w2 = (-3.0f * t3 + 3.0f * t2 + 3.0f * tt + 1.0f) * (1.0f / 6.0f); // k=i-1
        const float w3 = t3 * (1.0f / 6.0f);                                     // k=i

        // Table row for tap j is (k+PAD) = i+j -> base + compile-time offsets.
        const vf4* row = &sc[i * ROW_VF4 + lane];
        vf4 sf = w0 * row[0]
               + w1 * row[ROW_VF4]
               + w2 * row[2 * ROW_VF4]
               + w3 * row[3 * ROW_VF4];

        out4[idx] = xv[c] * sf * sf;           // plain store (A/B: no NT)
    }
}

extern "C" void kernel_launch(void* const* d_in, const int* in_sizes, int n_in,
                              void* d_out, int out_size, void* d_ws, size_t ws_size,
                              hipStream_t stream) {
    const float* eval_x = (const float*)d_in[0];  // [32,8192,128] fp32
    const float* eigs   = (const float*)d_in[1];  // [32,8192]     fp32
    const float* coeffs = (const float*)d_in[2];  // [12,128]      fp32
    float* out = (float*)d_out;

    const int total4  = in_sizes[0] / 4;                               // 8388608
    const int blocks  = (total4 + 256 * CHUNKS - 1) / (256 * CHUNKS);  // 8192
    const int stride4 = blocks * 256;
    const bool exact  = (blocks * 256 * CHUNKS == total4);

    if (exact) {
        spline_filter_kernel<true><<<blocks, 256, 0, stream>>>(
            (const vf4*)eval_x, eigs, (const vf4*)coeffs, (vf4*)out,
            total4, stride4);
    } else {
        spline_filter_kernel<false><<<blocks, 256, 0, stream>>>(
            (const vf4*)eval_x, eigs, (const vf4*)coeffs, (vf4*)out,
            total4, stride4);
    }
}

// Round 3
// 228.149 us; speedup vs baseline: 1.0355x; 1.0355x over previous
//
#include <hip/hip_runtime.h>

// SplineFilter: out[b,n,f] = eval_x[b,n,f] * sf^2,
//   sf = sum_k basis_k(eigs[b,n]) * coeffs[k,f]
// Cubic B-spline over uniform knots linspace(0,2,16), 12 bases; only 4
// nonzero taps per x (cardinal cubic weights in t = x*7.5 - i).
//
// R2 post-mortem: kernel counters showed 85 us @ 2.4 TB/s, VALUBusy 11%,
// VGPR_Count=32 -> the compiler SANK the up-front loads into the chunk
// bodies (32 regs can't hold 4x vf4 + 4x eigs in flight), serializing 4
// HBM latency exposures per thread. Latency-bound, not BW-bound.
// This round:
// - Loads issued BEFORE the LDS staging loop (overlap with staging +
//   barrier), then __builtin_amdgcn_sched_barrier(0) pins them: nothing
//   may move across, so all 8 streamed loads are in flight per thread.
// - NT load/store restored (R2 A/B: removing NT cost ~8 us).

#define N_BASES 12
#define F_CH 128
#define CHUNKS 4
#define PAD 3
#define TAB_ROWS (N_BASES + 2 * PAD)  // 18 rows: k = -3..14
#define ROW_VF4 (F_CH / 4)            // 32 vf4 per row

typedef float vf4 __attribute__((ext_vector_type(4)));

template <bool EXACT>
__global__ __launch_bounds__(256) void spline_filter_kernel(
    const vf4* __restrict__ x4,      // eval_x as vf4
    const float* __restrict__ eigs,  // [rows]
    const vf4* __restrict__ coeffs4, // [12*32]
    vf4*       __restrict__ out4,
    int total4, int stride4)
{
    __shared__ vf4 sc[TAB_ROWS * ROW_VF4];  // 9 KB, zero-padded

    const int t   = threadIdx.x;
    const int gid = blockIdx.x * 256 + t;

    float eg[CHUNKS];
    vf4   xv[CHUNKS];

    // ---- Issue ALL streamed loads first (before staging, before sync).
    #pragma unroll
    for (int c = 0; c < CHUNKS; ++c) {
        const int idx = gid + c * stride4;
        if (EXACT || idx < total4) eg[c] = eigs[idx >> 5];
        else                       eg[c] = 0.0f;
    }
    #pragma unroll
    for (int c = 0; c < CHUNKS; ++c) {
        const int idx = gid + c * stride4;
        if (EXACT || idx < total4) xv[c] = __builtin_nontemporal_load(&x4[idx]);
        else                       xv[c] = (vf4)0.0f;
    }
    // Pin: compiler may not sink these loads past this point.
    __builtin_amdgcn_sched_barrier(0);

    // ---- Stage zero-padded coeff table (overlaps the in-flight loads).
    for (int r = t; r < TAB_ROWS * ROW_VF4; r += 256) {
        const int k = (r >> 5) - PAD;
        sc[r] = ((unsigned)k < (unsigned)N_BASES)
                    ? coeffs4[k * ROW_VF4 + (r & 31)]
                    : (vf4)0.0f;
    }
    __syncthreads();

    // stride4 is a multiple of 32, so lane is chunk-invariant.
    const int lane = gid & 31;

    #pragma unroll
    for (int c = 0; c < CHUNKS; ++c) {
        const int idx = gid + c * stride4;
        if (!EXACT && idx >= total4) continue;

        // 4 nonzero cardinal cubic weights for x = eg[c]
        const float u = eg[c] * 7.5f;          // x / (2/15)
        int i = (int)u;
        i = min(max(i, 0), N_BASES + 2);       // rows i..i+3 stay in-table
        float tt = u - (float)i;
        tt = fminf(fmaxf(tt, 0.0f), 1.0f);     // OOB x -> all taps hit zero rows
        const float t2  = tt * tt;
        const float t3  = t2 * tt;
        const float omt = 1.0f - tt;
        const float w0 = omt * omt * omt * (1.0f / 6.0f);                        // k=i-3
        const float w1 = (3.0f * t3 - 6.0f * t2 + 4.0f) * (1.0f / 6.0f);         // k=i-2
        const float w2 = (-3.0f * t3 + 3.0f * t2 + 3.0f * tt + 1.0f) * (1.0f / 6.0f); // k=i-1
        const float w3 = t3 * (1.0f / 6.0f);                                     // k=i

        // Table row for tap j is (k+PAD) = i+j -> base + compile-time offsets.
        const vf4* row = &sc[i * ROW_VF4 + lane];
        vf4 sf = w0 * row[0]
               + w1 * row[ROW_VF4]
               + w2 * row[2 * ROW_VF4]
               + w3 * row[3 * ROW_VF4];

        const vf4 o = xv[c] * sf * sf;
        __builtin_nontemporal_store(o, &out4[idx]);
    }
}

extern "C" void kernel_launch(void* const* d_in, const int* in_sizes, int n_in,
                              void* d_out, int out_size, void* d_ws, size_t ws_size,
                              hipStream_t stream) {
    const float* eval_x = (const float*)d_in[0];  // [32,8192,128] fp32
    const float* eigs   = (const float*)d_in[1];  // [32,8192]     fp32
    const float* coeffs = (const float*)d_in[2];  // [12,128]      fp32
    float* out = (float*)d_out;

    const int total4  = in_sizes[0] / 4;                               // 8388608
    const int blocks  = (total4 + 256 * CHUNKS - 1) / (256 * CHUNKS);  // 8192
    const int stride4 = blocks * 256;
    const bool exact  = (blocks * 256 * CHUNKS == total4);

    if (exact) {
        spline_filter_kernel<true><<<blocks, 256, 0, stream>>>(
            (const vf4*)eval_x, eigs, (const vf4*)coeffs, (vf4*)out,
            total4, stride4);
    } else {
        spline_filter_kernel<false><<<blocks, 256, 0, stream>>>(
            (const vf4*)eval_x, eigs, (const vf4*)coeffs, (vf4*)out,
            total4, stride4);
    }
}

// Round 5
// 226.088 us; speedup vs baseline: 1.0449x; 1.0091x over previous
//
#include <hip/hip_runtime.h>

// SplineFilter: out[b,n,f] = eval_x[b,n,f] * sf^2,
//   sf = sum_k basis_k(eigs[b,n]) * coeffs[k,f]
// Cubic B-spline over uniform knots linspace(0,2,16), 12 bases; only 4
// nonzero taps per x (cardinal cubic weights in t = x*7.5 - i).
//
// R3 post-mortem: fixed-overhead model -> kernel ~77us = 3.5 TB/s, and
// R2's direct counters (VALUBusy 11%, hbm 29%, occ 70%) say nothing is
// saturated: latency/MLP-bound. Source-level ILP knobs were all neutral.
// This round: restructure to the shape of the 6.6 TB/s fill kernel --
// pure TLP streaming:
// - NO LDS, NO barrier. Coeff table is 6 KB -> L1-resident per CU; the
//   4 tap reads are L1 hits. Removes the per-block staging+sync chain.
// - 16384 blocks x 256 thr, CHUNKS=2, all 4 streamed loads issued up
//   front. __launch_bounds__(256,8) pins VGPR<=64 -> 32 waves/CU.
// - Per-tap clamp+select for boundary (VALU is 11% busy -- free).
// - NT load/store on the streams (R2 A/B: worth ~8 us).
//
// (R4 was an infra failure -- container died before running; identical
// kernel resubmitted.)

#define N_BASES 12
#define F_CH 128
#define CHUNKS 2
#define ROW_VF4 (F_CH / 4)  // 32 vf4 per coeff row

typedef float vf4 __attribute__((ext_vector_type(4)));

template <bool EXACT>
__global__ __launch_bounds__(256, 8) void spline_filter_kernel(
    const vf4* __restrict__ x4,      // eval_x as vf4
    const float* __restrict__ eigs,  // [rows]
    const vf4* __restrict__ coeffs4, // [12*32]
    vf4*       __restrict__ out4,
    int total4, int stride4)
{
    const int gid = blockIdx.x * 256 + threadIdx.x;

    float eg[CHUNKS];
    vf4   xv[CHUNKS];

    // Issue all streamed loads up front (independent, all in flight).
    #pragma unroll
    for (int c = 0; c < CHUNKS; ++c) {
        const int idx = gid + c * stride4;
        if (EXACT || idx < total4) eg[c] = eigs[idx >> 5];
        else                       eg[c] = 0.0f;
    }
    #pragma unroll
    for (int c = 0; c < CHUNKS; ++c) {
        const int idx = gid + c * stride4;
        if (EXACT || idx < total4) xv[c] = __builtin_nontemporal_load(&x4[idx]);
        else                       xv[c] = (vf4)0.0f;
    }

    // stride4 is a multiple of 32, so lane is chunk-invariant.
    const int lane = gid & 31;

    #pragma unroll
    for (int c = 0; c < CHUNKS; ++c) {
        const int idx = gid + c * stride4;
        if (!EXACT && idx >= total4) continue;

        // 4 nonzero cardinal cubic weights for x = eg[c].
        // Clamp u to [0,15]: keeps tt in [0,1] (finite weights) while the
        // per-tap validity select still zeroes everything for OOB x.
        float u = eg[c] * 7.5f;                 // x / (2/15)
        u = fminf(fmaxf(u, 0.0f), 15.0f);
        const int   i  = (int)u;
        const float tt = u - (float)i;
        const float t2  = tt * tt;
        const float t3  = t2 * tt;
        const float omt = 1.0f - tt;
        float w[4];
        w[0] = omt * omt * omt * (1.0f / 6.0f);                             // k=i-3
        w[1] = (3.0f * t3 - 6.0f * t2 + 4.0f) * (1.0f / 6.0f);              // k=i-2
        w[2] = (-3.0f * t3 + 3.0f * t2 + 3.0f * tt + 1.0f) * (1.0f / 6.0f); // k=i-1
        w[3] = t3 * (1.0f / 6.0f);                                          // k=i

        vf4 sf = (vf4)0.0f;
        #pragma unroll
        for (int j = 0; j < 4; ++j) {
            const int k  = i - 3 + j;
            const int kc = min(max(k, 0), N_BASES - 1);
            const float wj = (k == kc) ? w[j] : 0.0f;   // zero if clamped
            sf += wj * coeffs4[kc * ROW_VF4 + lane];    // L1-hit (6 KB table)
        }

        const vf4 o = xv[c] * sf * sf;
        __builtin_nontemporal_store(o, &out4[idx]);
    }
}

extern "C" void kernel_launch(void* const* d_in, const int* in_sizes, int n_in,
                              void* d_out, int out_size, void* d_ws, size_t ws_size,
                              hipStream_t stream) {
    const float* eval_x = (const float*)d_in[0];  // [32,8192,128] fp32
    const float* eigs   = (const float*)d_in[1];  // [32,8192]     fp32
    const float* coeffs = (const float*)d_in[2];  // [12,128]      fp32
    float* out = (float*)d_out;

    const int total4  = in_sizes[0] / 4;                               // 8388608
    const int blocks  = (total4 + 256 * CHUNKS - 1) / (256 * CHUNKS);  // 16384
    const int stride4 = blocks * 256;
    const bool exact  = (blocks * 256 * CHUNKS == total4);

    if (exact) {
        spline_filter_kernel<true><<<blocks, 256, 0, stream>>>(
            (const vf4*)eval_x, eigs, (const vf4*)coeffs, (vf4*)out,
            total4, stride4);
    } else {
        spline_filter_kernel<false><<<blocks, 256, 0, stream>>>(
            (const vf4*)eval_x, eigs, (const vf4*)coeffs, (vf4*)out,
            total4, stride4);
    }
}